// Round 1
// baseline (2337.910 us; speedup 1.0000x reference)
//
#include <hip/hip_runtime.h>

#define N_NODES 50000
#define N_EDGES 800000
#define F_IN    128
#define HID     128
#define OUT_F   64
#define N_GROUPS 512

// ---------------------------------------------------------------- degree ----
__global__ __launch_bounds__(256) void k_deg(const int* __restrict__ col,
                                             float* __restrict__ deg) {
    int e = blockIdx.x * 256 + threadIdx.x;
    if (e < N_EDGES) atomicAdd(&deg[col[e]], 1.0f);
}

__global__ __launch_bounds__(256) void k_dis(float* __restrict__ deg) {
    int n = blockIdx.x * 256 + threadIdx.x;
    if (n < N_NODES) {
        float d = deg[n];
        deg[n] = d > 0.f ? 1.0f / sqrtf(d) : 0.f;
    }
}

// ------------------------------------------------------------- dual GEMM ----
// Computes O0 = A @ B0 and O1 = A @ B1 + (bias_c + bias_b), A: [N_NODES,128].
// Block tile: 64 rows x 64 cols, blockDim (16,16), 4x4 accum per thread.
// A-tile staged in LDS with stride 132 (bank-conflict padding).
__global__ __launch_bounds__(256) void k_gemm_dual(
    const float* __restrict__ A,
    const float* __restrict__ B0, const float* __restrict__ B1,
    const float* __restrict__ bias_c, const float* __restrict__ bias_b,
    float* __restrict__ O0, float* __restrict__ O1,
    int C, int tilesPerMat)
{
    __shared__ float lds[64 * 132];
    const int rowBase = blockIdx.x * 64;
    const int ct = blockIdx.y;
    const int mat = (ct >= tilesPerMat) ? 1 : 0;
    const int colBase = (mat ? (ct - tilesPerMat) : ct) * 64;
    const float* __restrict__ B = mat ? B1 : B0;
    float* __restrict__ O = mat ? O1 : O0;

    const int tx = threadIdx.x, ty = threadIdx.y;
    const int tid = ty * 16 + tx;

    // stage A tile (64 x 128) -> LDS
    {
        const int r0 = tid >> 5;          // 0..7
        const int c4 = (tid & 31) << 2;   // 0..124
        #pragma unroll
        for (int i = 0; i < 8; ++i) {
            int rr = r0 + i * 8;
            int g = rowBase + rr;
            float4 v = make_float4(0.f, 0.f, 0.f, 0.f);
            if (g < N_NODES) v = *(const float4*)(A + (size_t)g * 128 + c4);
            *(float4*)(&lds[rr * 132 + c4]) = v;
        }
    }
    __syncthreads();

    float acc[4][4];
    #pragma unroll
    for (int i = 0; i < 4; ++i)
        #pragma unroll
        for (int j = 0; j < 4; ++j) acc[i][j] = 0.f;

    const float* __restrict__ Bp = B + colBase + tx * 4;
    const float* lA = &lds[(ty * 4) * 132];

    #pragma unroll 8
    for (int k = 0; k < 128; ++k) {
        float4 b = *(const float4*)(Bp + (size_t)k * C);
        float a0 = lA[k];
        float a1 = lA[132 + k];
        float a2 = lA[264 + k];
        float a3 = lA[396 + k];
        acc[0][0] += a0 * b.x; acc[0][1] += a0 * b.y; acc[0][2] += a0 * b.z; acc[0][3] += a0 * b.w;
        acc[1][0] += a1 * b.x; acc[1][1] += a1 * b.y; acc[1][2] += a1 * b.z; acc[1][3] += a1 * b.w;
        acc[2][0] += a2 * b.x; acc[2][1] += a2 * b.y; acc[2][2] += a2 * b.z; acc[2][3] += a2 * b.w;
        acc[3][0] += a3 * b.x; acc[3][1] += a3 * b.y; acc[3][2] += a3 * b.z; acc[3][3] += a3 * b.w;
    }

    float badd[4] = {0.f, 0.f, 0.f, 0.f};
    if (mat) {
        int cb = colBase + tx * 4;
        #pragma unroll
        for (int j = 0; j < 4; ++j) badd[j] = bias_c[cb + j] + bias_b[cb + j];
    }

    const int colg = colBase + tx * 4;
    const int gr = rowBase + ty * 4;
    #pragma unroll
    for (int i = 0; i < 4; ++i) {
        int g = gr + i;
        if (g < N_NODES) {
            float4 o;
            o.x = acc[i][0] + badd[0];
            o.y = acc[i][1] + badd[1];
            o.z = acc[i][2] + badd[2];
            o.w = acc[i][3] + badd[3];
            *(float4*)(O + (size_t)g * C + colg) = o;
        }
    }
}

// ---------------------------------------------------------- edge scatter ----
// dst[col[e], :] += dis[row[e]]*dis[col[e]] * src[row[e], :]
template<int C, int LOGL>
__global__ __launch_bounds__(256) void k_scatter(
    const int* __restrict__ row, const int* __restrict__ col,
    const float* __restrict__ dis, const float* __restrict__ src,
    float* __restrict__ dst)
{
    int gid = blockIdx.x * 256 + threadIdx.x;
    int e = gid >> LOGL;
    if (e >= N_EDGES) return;
    int f4 = (gid & ((1 << LOGL) - 1)) << 2;
    int r = row[e], c = col[e];
    float nrm = dis[r] * dis[c];
    float4 v = *(const float4*)(src + (size_t)r * C + f4);
    float* d = dst + (size_t)c * C + f4;
    atomicAdd(d + 0, nrm * v.x);
    atomicAdd(d + 1, nrm * v.y);
    atomicAdd(d + 2, nrm * v.z);
    atomicAdd(d + 3, nrm * v.w);
}

// ------------------------------------------------------------ h1 = relu -----
__global__ __launch_bounds__(256) void k_h1(float* __restrict__ agg,
                                            const float* __restrict__ lin) {
    int i4 = (blockIdx.x * 256 + threadIdx.x) * 4;
    if (i4 < N_NODES * 128) {
        float4 a = *(float4*)(agg + i4);
        float4 l = *(const float4*)(lin + i4);
        a.x = fmaxf(a.x + l.x, 0.f);
        a.y = fmaxf(a.y + l.y, 0.f);
        a.z = fmaxf(a.z + l.z, 0.f);
        a.w = fmaxf(a.w + l.w, 0.f);
        *(float4*)(agg + i4) = a;
    }
}

// --------------------------------------------- h2 = agg2+lin2, pool by group
__global__ __launch_bounds__(256) void k_pool(
    const float* __restrict__ agg2, const float* __restrict__ lin2,
    const int* __restrict__ group, float* __restrict__ pooled)
{
    int gid = blockIdx.x * 256 + threadIdx.x;   // over N_NODES*16 (float4 per thread)
    if (gid >= N_NODES * 16) return;
    int n = gid >> 4;
    int f4 = (gid & 15) << 2;
    int idx = n * 64 + f4;
    float4 a = *(const float4*)(agg2 + idx);
    float4 l = *(const float4*)(lin2 + idx);
    float* p = pooled + group[n] * 64 + f4;
    atomicAdd(p + 0, a.x + l.x);
    atomicAdd(p + 1, a.y + l.y);
    atomicAdd(p + 2, a.z + l.z);
    atomicAdd(p + 3, a.w + l.w);
}

// ----------------------------------------------------- head: relu @ Wh + bh -
__global__ __launch_bounds__(64) void k_head(
    const float* __restrict__ pooled, const float* __restrict__ Wh,
    const float* __restrict__ bh, float* __restrict__ out)
{
    int g = blockIdx.x;
    int f = threadIdx.x;
    float v = fmaxf(pooled[g * 64 + f], 0.f) * Wh[f];
    #pragma unroll
    for (int off = 32; off > 0; off >>= 1) v += __shfl_down(v, off);
    if (f == 0) out[g] = v + bh[0];
}

// ---------------------------------------------------------------------------
extern "C" void kernel_launch(void* const* d_in, const int* in_sizes, int n_in,
                              void* d_out, int out_size, void* d_ws, size_t ws_size,
                              hipStream_t stream) {
    const float* x  = (const float*)d_in[0];
    const int*   ei = (const int*)d_in[1];
    const int*  grp = (const int*)d_in[2];
    const float* W1 = (const float*)d_in[3];
    const float* b1 = (const float*)d_in[4];
    const float* L1 = (const float*)d_in[5];
    const float* c1 = (const float*)d_in[6];
    const float* W2 = (const float*)d_in[7];
    const float* b2 = (const float*)d_in[8];
    const float* L2 = (const float*)d_in[9];
    const float* c2 = (const float*)d_in[10];
    const float* Wh = (const float*)d_in[11];
    const float* bh = (const float*)d_in[12];
    float* out = (float*)d_out;

    const int* row  = ei;             // edge_index[0] = source
    const int* colp = ei + N_EDGES;   // edge_index[1] = target

    // ws layout (floats):
    float* ws     = (float*)d_ws;
    float* dis    = ws;                       // 50000 (deg -> 1/sqrt(deg) in place)
    float* xw1    = ws + 50048;               // 6.4M
    float* lin1   = xw1 + 6400000;            // 6.4M
    float* agg1   = lin1 + 6400000;           // 6.4M (becomes h1, then first half becomes agg2)
    float* pooled = agg1 + 6400000;           // 32768
    float* hw2    = xw1;                      // reuse
    float* lin2   = lin1;                     // reuse
    float* agg2   = agg1;                     // reuse (after gemm2 consumed h1)

    hipMemsetAsync(dis, 0, N_NODES * sizeof(float), stream);
    hipMemsetAsync(agg1, 0, (size_t)N_NODES * 128 * sizeof(float), stream);
    hipMemsetAsync(pooled, 0, (size_t)N_GROUPS * 64 * sizeof(float), stream);

    k_deg<<<(N_EDGES + 255) / 256, 256, 0, stream>>>(colp, dis);
    k_dis<<<(N_NODES + 255) / 256, 256, 0, stream>>>(dis);

    dim3 blk(16, 16);
    // layer 1: xw1 = x@W1 ; lin1 = x@L1 + c1 + b1
    k_gemm_dual<<<dim3(782, 4), blk, 0, stream>>>(x, W1, L1, c1, b1, xw1, lin1, 128, 2);
    k_scatter<128, 5><<<(N_EDGES * 32) / 256, 256, 0, stream>>>(row, colp, dis, xw1, agg1);
    k_h1<<<(N_NODES * 128 / 4 + 255) / 256, 256, 0, stream>>>(agg1, lin1);   // h1 in agg1

    // layer 2: hw2 = h1@W2 ; lin2 = h1@L2 + c2 + b2
    k_gemm_dual<<<dim3(782, 2), blk, 0, stream>>>(agg1, W2, L2, c2, b2, hw2, lin2, 64, 1);
    hipMemsetAsync(agg2, 0, (size_t)N_NODES * 64 * sizeof(float), stream);
    k_scatter<64, 4><<<(N_EDGES * 16) / 256, 256, 0, stream>>>(row, colp, dis, hw2, agg2);

    k_pool<<<(N_NODES * 16 + 255) / 256, 256, 0, stream>>>(agg2, lin2, grp, pooled);
    k_head<<<N_GROUPS, 64, 0, stream>>>(pooled, Wh, bh, out);
}

// Round 2
// 519.443 us; speedup vs baseline: 4.5008x; 4.5008x over previous
//
#include <hip/hip_runtime.h>

#define N_NODES 50000
#define N_EDGES 800000
#define F_IN    128
#define HID     128
#define OUT_F   64
#define N_GROUPS 512

// ------------------------------------------------------- degree histogram ----
__global__ __launch_bounds__(256) void k_deg(const int* __restrict__ col,
                                             int* __restrict__ ideg) {
    int e = blockIdx.x * 256 + threadIdx.x;
    if (e < N_EDGES) atomicAdd(&ideg[col[e]], 1);
}

__global__ __launch_bounds__(256) void k_dis(const int* __restrict__ ideg,
                                             float* __restrict__ dis) {
    int n = blockIdx.x * 256 + threadIdx.x;
    if (n < N_NODES) {
        int d = ideg[n];
        dis[n] = d > 0 ? rsqrtf((float)d) : 0.f;
    }
}

// ------------------------------------------- exclusive scan (single block) ---
// 1024 threads, each handles CHUNK sequential elements; Hillis-Steele in LDS.
#define SCAN_CHUNK 49
__global__ __launch_bounds__(1024) void k_scan(const int* __restrict__ ideg,
                                               int* __restrict__ rowptr,
                                               int* __restrict__ cursor) {
    __shared__ int psum[1024];
    const int t = threadIdx.x;
    const int base = t * SCAN_CHUNK;
    int s = 0;
    for (int i = 0; i < SCAN_CHUNK; ++i) {
        int idx = base + i;
        if (idx < N_NODES) s += ideg[idx];
    }
    psum[t] = s;
    __syncthreads();
    for (int off = 1; off < 1024; off <<= 1) {
        int v = 0;
        if (t >= off) v = psum[t - off];
        __syncthreads();
        if (t >= off) psum[t] += v;
        __syncthreads();
    }
    int run = (t == 0) ? 0 : psum[t - 1];
    for (int i = 0; i < SCAN_CHUNK; ++i) {
        int idx = base + i;
        if (idx < N_NODES) {
            rowptr[idx] = run;
            cursor[idx] = run;
            run += ideg[idx];
        } else if (idx == N_NODES) {
            rowptr[idx] = run;  // total
        }
    }
}

// --------------------------------------------------------------- CSR fill ----
// esrc[pos] = source node, ew[pos] = dis[source]  (bucket order arbitrary)
__global__ __launch_bounds__(256) void k_fill(
    const int* __restrict__ row, const int* __restrict__ col,
    const float* __restrict__ dis,
    int* __restrict__ cursor, int* __restrict__ esrc, float* __restrict__ ew) {
    int e = blockIdx.x * 256 + threadIdx.x;
    if (e < N_EDGES) {
        int r = row[e], c = col[e];
        int pos = atomicAdd(&cursor[c], 1);
        esrc[pos] = r;
        ew[pos] = dis[r];
    }
}

// ------------------------------------------------------------- dual GEMM ----
// O0 = A @ B0 ; O1 = A @ B1 + (bias_c + bias_b). A: [N_NODES,128].
// 64x64 tile, blockDim (16,16), 4x4 accum/thread, LDS stride 132.
__global__ __launch_bounds__(256) void k_gemm_dual(
    const float* __restrict__ A,
    const float* __restrict__ B0, const float* __restrict__ B1,
    const float* __restrict__ bias_c, const float* __restrict__ bias_b,
    float* __restrict__ O0, float* __restrict__ O1,
    int C, int tilesPerMat)
{
    __shared__ float lds[64 * 132];
    const int rowBase = blockIdx.x * 64;
    const int ct = blockIdx.y;
    const int mat = (ct >= tilesPerMat) ? 1 : 0;
    const int colBase = (mat ? (ct - tilesPerMat) : ct) * 64;
    const float* __restrict__ B = mat ? B1 : B0;
    float* __restrict__ O = mat ? O1 : O0;

    const int tx = threadIdx.x, ty = threadIdx.y;
    const int tid = ty * 16 + tx;

    {
        const int r0 = tid >> 5;
        const int c4 = (tid & 31) << 2;
        #pragma unroll
        for (int i = 0; i < 8; ++i) {
            int rr = r0 + i * 8;
            int g = rowBase + rr;
            float4 v = make_float4(0.f, 0.f, 0.f, 0.f);
            if (g < N_NODES) v = *(const float4*)(A + (size_t)g * 128 + c4);
            *(float4*)(&lds[rr * 132 + c4]) = v;
        }
    }
    __syncthreads();

    float acc[4][4];
    #pragma unroll
    for (int i = 0; i < 4; ++i)
        #pragma unroll
        for (int j = 0; j < 4; ++j) acc[i][j] = 0.f;

    const float* __restrict__ Bp = B + colBase + tx * 4;
    const float* lA = &lds[(ty * 4) * 132];

    #pragma unroll 8
    for (int k = 0; k < 128; ++k) {
        float4 b = *(const float4*)(Bp + (size_t)k * C);
        float a0 = lA[k];
        float a1 = lA[132 + k];
        float a2 = lA[264 + k];
        float a3 = lA[396 + k];
        acc[0][0] += a0 * b.x; acc[0][1] += a0 * b.y; acc[0][2] += a0 * b.z; acc[0][3] += a0 * b.w;
        acc[1][0] += a1 * b.x; acc[1][1] += a1 * b.y; acc[1][2] += a1 * b.z; acc[1][3] += a1 * b.w;
        acc[2][0] += a2 * b.x; acc[2][1] += a2 * b.y; acc[2][2] += a2 * b.z; acc[2][3] += a2 * b.w;
        acc[3][0] += a3 * b.x; acc[3][1] += a3 * b.y; acc[3][2] += a3 * b.z; acc[3][3] += a3 * b.w;
    }

    float badd[4] = {0.f, 0.f, 0.f, 0.f};
    if (mat) {
        int cb = colBase + tx * 4;
        #pragma unroll
        for (int j = 0; j < 4; ++j) badd[j] = bias_c[cb + j] + bias_b[cb + j];
    }

    const int colg = colBase + tx * 4;
    const int gr = rowBase + ty * 4;
    #pragma unroll
    for (int i = 0; i < 4; ++i) {
        int g = gr + i;
        if (g < N_NODES) {
            float4 o;
            o.x = acc[i][0] + badd[0];
            o.y = acc[i][1] + badd[1];
            o.z = acc[i][2] + badd[2];
            o.w = acc[i][3] + badd[3];
            *(float4*)(O + (size_t)g * C + colg) = o;
        }
    }
}

// -------------------------------------------- layer-1 gather + lin + relu ---
// h1[n,f] = relu(dis[n] * sum_e ew[e]*xw1[esrc[e],f] + lin1[n,f])  (in place)
__global__ __launch_bounds__(128) void k_gather1(
    const int* __restrict__ rowptr, const int* __restrict__ esrc,
    const float* __restrict__ ew, const float* __restrict__ dis,
    const float* __restrict__ xw1, float* __restrict__ lin1_h1) {
    const int n = blockIdx.x;
    const int f = threadIdx.x;
    const int start = rowptr[n], end = rowptr[n + 1];
    float acc = 0.f;
    int e = start;
    for (; e + 4 <= end; e += 4) {
        int r0 = esrc[e], r1 = esrc[e + 1], r2 = esrc[e + 2], r3 = esrc[e + 3];
        float w0 = ew[e], w1 = ew[e + 1], w2 = ew[e + 2], w3 = ew[e + 3];
        float v0 = xw1[(size_t)r0 * 128 + f];
        float v1 = xw1[(size_t)r1 * 128 + f];
        float v2 = xw1[(size_t)r2 * 128 + f];
        float v3 = xw1[(size_t)r3 * 128 + f];
        acc += w0 * v0 + w1 * v1 + w2 * v2 + w3 * v3;
    }
    for (; e < end; ++e) {
        acc += ew[e] * xw1[(size_t)esrc[e] * 128 + f];
    }
    size_t o = (size_t)n * 128 + f;
    lin1_h1[o] = fmaxf(dis[n] * acc + lin1_h1[o], 0.f);
}

// ------------------------------- layer-2 gather + lin + pool-by-group add ---
// h2[n,f] = dis[n]*sum ew*hw2[src,f] + lin2[n,f]; pooled[group[n],f] += h2
__global__ __launch_bounds__(128) void k_gather2(
    const int* __restrict__ rowptr, const int* __restrict__ esrc,
    const float* __restrict__ ew, const float* __restrict__ dis,
    const float* __restrict__ hw2, const float* __restrict__ lin2,
    const int* __restrict__ group, float* __restrict__ pooled) {
    const int n = blockIdx.x * 2 + (threadIdx.x >> 6);
    const int f = threadIdx.x & 63;
    if (n >= N_NODES) return;
    const int start = rowptr[n], end = rowptr[n + 1];
    float acc = 0.f;
    int e = start;
    for (; e + 4 <= end; e += 4) {
        int r0 = esrc[e], r1 = esrc[e + 1], r2 = esrc[e + 2], r3 = esrc[e + 3];
        float w0 = ew[e], w1 = ew[e + 1], w2 = ew[e + 2], w3 = ew[e + 3];
        float v0 = hw2[(size_t)r0 * 64 + f];
        float v1 = hw2[(size_t)r1 * 64 + f];
        float v2 = hw2[(size_t)r2 * 64 + f];
        float v3 = hw2[(size_t)r3 * 64 + f];
        acc += w0 * v0 + w1 * v1 + w2 * v2 + w3 * v3;
    }
    for (; e < end; ++e) {
        acc += ew[e] * hw2[(size_t)esrc[e] * 64 + f];
    }
    float h2 = dis[n] * acc + lin2[(size_t)n * 64 + f];
    atomicAdd(&pooled[(size_t)group[n] * 64 + f], h2);
}

// ----------------------------------------------------- head: relu @ Wh + bh -
__global__ __launch_bounds__(64) void k_head(
    const float* __restrict__ pooled, const float* __restrict__ Wh,
    const float* __restrict__ bh, float* __restrict__ out)
{
    int g = blockIdx.x;
    int f = threadIdx.x;
    float v = fmaxf(pooled[g * 64 + f], 0.f) * Wh[f];
    #pragma unroll
    for (int off = 32; off > 0; off >>= 1) v += __shfl_down(v, off);
    if (f == 0) out[g] = v + bh[0];
}

// ---------------------------------------------------------------------------
extern "C" void kernel_launch(void* const* d_in, const int* in_sizes, int n_in,
                              void* d_out, int out_size, void* d_ws, size_t ws_size,
                              hipStream_t stream) {
    const float* x  = (const float*)d_in[0];
    const int*   ei = (const int*)d_in[1];
    const int*  grp = (const int*)d_in[2];
    const float* W1 = (const float*)d_in[3];
    const float* b1 = (const float*)d_in[4];
    const float* L1 = (const float*)d_in[5];
    const float* c1 = (const float*)d_in[6];
    const float* W2 = (const float*)d_in[7];
    const float* b2 = (const float*)d_in[8];
    const float* L2 = (const float*)d_in[9];
    const float* c2 = (const float*)d_in[10];
    const float* Wh = (const float*)d_in[11];
    const float* bh = (const float*)d_in[12];
    float* out = (float*)d_out;

    const int* row  = ei;             // edge_index[0] = source
    const int* colp = ei + N_EDGES;   // edge_index[1] = target

    // ws layout
    char* p = (char*)d_ws;
    float* dis    = (float*)p;             p += 50048 * 4;
    int*   ideg   = (int*)p;               p += 50048 * 4;
    int*   rowptr = (int*)p;               p += 50052 * 4;
    int*   cursor = (int*)p;               p += 50048 * 4;
    int*   esrc   = (int*)p;               p += 800000 * 4;
    float* ew     = (float*)p;             p += 800000 * 4;
    float* xw1    = (float*)p;             p += (size_t)N_NODES * 128 * 4;
    float* lin1   = (float*)p;             p += (size_t)N_NODES * 128 * 4;
    float* pooled = (float*)p;             p += N_GROUPS * 64 * 4;
    // layer-2 outputs reuse xw1's slot (h1 lives in lin1)
    float* hw2  = xw1;
    float* lin2 = xw1 + (size_t)N_NODES * 64;

    hipMemsetAsync(ideg, 0, N_NODES * sizeof(int), stream);
    hipMemsetAsync(pooled, 0, (size_t)N_GROUPS * 64 * sizeof(float), stream);

    // CSR build
    k_deg<<<(N_EDGES + 255) / 256, 256, 0, stream>>>(colp, ideg);
    k_dis<<<(N_NODES + 255) / 256, 256, 0, stream>>>(ideg, dis);
    k_scan<<<1, 1024, 0, stream>>>(ideg, rowptr, cursor);
    k_fill<<<(N_EDGES + 255) / 256, 256, 0, stream>>>(row, colp, dis, cursor, esrc, ew);

    dim3 blk(16, 16);
    // layer 1: xw1 = x@W1 ; lin1 = x@L1 + c1 + b1
    k_gemm_dual<<<dim3(782, 4), blk, 0, stream>>>(x, W1, L1, c1, b1, xw1, lin1, 128, 2);
    k_gather1<<<N_NODES, 128, 0, stream>>>(rowptr, esrc, ew, dis, xw1, lin1); // h1 in lin1

    // layer 2: hw2 = h1@W2 ; lin2 = h1@L2 + c2 + b2
    k_gemm_dual<<<dim3(782, 2), blk, 0, stream>>>(lin1, W2, L2, c2, b2, hw2, lin2, 64, 1);
    k_gather2<<<(N_NODES + 1) / 2, 128, 0, stream>>>(rowptr, esrc, ew, dis, hw2, lin2, grp, pooled);

    k_head<<<N_GROUPS, 64, 0, stream>>>(pooled, Wh, bh, out);
}

// Round 5
// 382.606 us; speedup vs baseline: 6.1105x; 1.3576x over previous
//
#include <hip/hip_runtime.h>

#define N_NODES 50000
#define N_EDGES 800000
#define F_IN    128
#define HID     128
#define OUT_F   64
#define N_GROUPS 512

#define SCAN_BLK 49   // ceil(50000 / 1024)

// ------------------------------------------------------- degree histogram ----
__global__ __launch_bounds__(256) void k_deg(const int* __restrict__ col,
                                             int* __restrict__ ideg) {
    int e = blockIdx.x * 256 + threadIdx.x;
    if (e < N_EDGES) atomicAdd(&ideg[col[e]], 1);
}

// ------------------------------------------------ scan phase A: block sums ---
__global__ __launch_bounds__(256) void k_scanA(const int* __restrict__ ideg,
                                               int* __restrict__ blocksum) {
    __shared__ int lsum[4];
    const int t = threadIdx.x;
    const int base = blockIdx.x * 1024 + t * 4;
    int s = 0;
    if (base + 3 < N_NODES) {
        int4 v = *(const int4*)(ideg + base);
        s = v.x + v.y + v.z + v.w;
    } else {
        for (int i = 0; i < 4; ++i)
            if (base + i < N_NODES) s += ideg[base + i];
    }
    #pragma unroll
    for (int off = 32; off > 0; off >>= 1) s += __shfl_down(s, off);
    if ((t & 63) == 0) lsum[t >> 6] = s;
    __syncthreads();
    if (t == 0) blocksum[blockIdx.x] = lsum[0] + lsum[1] + lsum[2] + lsum[3];
}

// ------------------------------- scan phase B: scan the 49 block sums --------
__global__ __launch_bounds__(64) void k_scanB(const int* __restrict__ blocksum,
                                              int* __restrict__ blockoff,
                                              int* __restrict__ rowptr) {
    const int t = threadIdx.x;
    int orig = (t < SCAN_BLK) ? blocksum[t] : 0;
    int v = orig;
    #pragma unroll
    for (int off = 1; off < 64; off <<= 1) {
        int u = __shfl_up(v, off);
        if (t >= off) v += u;
    }
    if (t < SCAN_BLK) blockoff[t] = v - orig;       // exclusive
    if (t == SCAN_BLK - 1) rowptr[N_NODES] = v;     // grand total
}

// --------------- scan phase C: per-element exclusive scan + dis, fused -------
__global__ __launch_bounds__(256) void k_scanC(const int* __restrict__ ideg,
                                               const int* __restrict__ blockoff,
                                               int* __restrict__ rowptr,
                                               int* __restrict__ cursor,
                                               float* __restrict__ dis) {
    __shared__ int psum[256];
    const int t = threadIdx.x;
    const int base = blockIdx.x * 1024 + t * 4;
    int d[4] = {0, 0, 0, 0};
    if (base + 3 < N_NODES) {
        int4 v = *(const int4*)(ideg + base);
        d[0] = v.x; d[1] = v.y; d[2] = v.z; d[3] = v.w;
    } else {
        for (int i = 0; i < 4; ++i)
            if (base + i < N_NODES) d[i] = ideg[base + i];
    }
    psum[t] = d[0] + d[1] + d[2] + d[3];
    __syncthreads();
    for (int off = 1; off < 256; off <<= 1) {
        int v = 0;
        if (t >= off) v = psum[t - off];
        __syncthreads();
        if (t >= off) psum[t] += v;
        __syncthreads();
    }
    int run = blockoff[blockIdx.x] + ((t == 0) ? 0 : psum[t - 1]);
    #pragma unroll
    for (int i = 0; i < 4; ++i) {
        int idx = base + i;
        if (idx < N_NODES) {
            rowptr[idx] = run;
            cursor[idx] = run;
            dis[idx] = d[i] > 0 ? rsqrtf((float)d[i]) : 0.f;
            run += d[i];
        }
    }
}

// --------------------------------------------------------------- CSR fill ----
// edge[pos] = {src, float_bits(dis[src])} — one 8B scattered store per edge.
__global__ __launch_bounds__(256) void k_fill(
    const int* __restrict__ row, const int* __restrict__ col,
    const float* __restrict__ dis,
    int* __restrict__ cursor, int2* __restrict__ edge) {
    int e = blockIdx.x * 256 + threadIdx.x;
    if (e < N_EDGES) {
        int r = row[e], c = col[e];
        int pos = atomicAdd(&cursor[c], 1);
        edge[pos] = make_int2(r, __float_as_int(dis[r]));
    }
}

// ------------------------------------------------------------- dual GEMM ----
// O0 = A @ B0 ; O1 = A @ B1 + (bias_c + bias_b). A: [N_NODES,128].
// 64x64 tile, blockDim (16,16), 4x4 accum/thread, LDS stride 132.
__global__ __launch_bounds__(256) void k_gemm_dual(
    const float* __restrict__ A,
    const float* __restrict__ B0, const float* __restrict__ B1,
    const float* __restrict__ bias_c, const float* __restrict__ bias_b,
    float* __restrict__ O0, float* __restrict__ O1,
    int C, int tilesPerMat)
{
    __shared__ float lds[64 * 132];
    const int rowBase = blockIdx.x * 64;
    const int ct = blockIdx.y;
    const int mat = (ct >= tilesPerMat) ? 1 : 0;
    const int colBase = (mat ? (ct - tilesPerMat) : ct) * 64;
    const float* __restrict__ B = mat ? B1 : B0;
    float* __restrict__ O = mat ? O1 : O0;

    const int tx = threadIdx.x, ty = threadIdx.y;
    const int tid = ty * 16 + tx;

    {
        const int r0 = tid >> 5;
        const int c4 = (tid & 31) << 2;
        #pragma unroll
        for (int i = 0; i < 8; ++i) {
            int rr = r0 + i * 8;
            int g = rowBase + rr;
            float4 v = make_float4(0.f, 0.f, 0.f, 0.f);
            if (g < N_NODES) v = *(const float4*)(A + (size_t)g * 128 + c4);
            *(float4*)(&lds[rr * 132 + c4]) = v;
        }
    }
    __syncthreads();

    float acc[4][4];
    #pragma unroll
    for (int i = 0; i < 4; ++i)
        #pragma unroll
        for (int j = 0; j < 4; ++j) acc[i][j] = 0.f;

    const float* __restrict__ Bp = B + colBase + tx * 4;
    const float* lA = &lds[(ty * 4) * 132];

    #pragma unroll 8
    for (int k = 0; k < 128; ++k) {
        float4 b = *(const float4*)(Bp + (size_t)k * C);
        float a0 = lA[k];
        float a1 = lA[132 + k];
        float a2 = lA[264 + k];
        float a3 = lA[396 + k];
        acc[0][0] += a0 * b.x; acc[0][1] += a0 * b.y; acc[0][2] += a0 * b.z; acc[0][3] += a0 * b.w;
        acc[1][0] += a1 * b.x; acc[1][1] += a1 * b.y; acc[1][2] += a1 * b.z; acc[1][3] += a1 * b.w;
        acc[2][0] += a2 * b.x; acc[2][1] += a2 * b.y; acc[2][2] += a2 * b.z; acc[2][3] += a2 * b.w;
        acc[3][0] += a3 * b.x; acc[3][1] += a3 * b.y; acc[3][2] += a3 * b.z; acc[3][3] += a3 * b.w;
    }

    float badd[4] = {0.f, 0.f, 0.f, 0.f};
    if (mat) {
        int cb = colBase + tx * 4;
        #pragma unroll
        for (int j = 0; j < 4; ++j) badd[j] = bias_c[cb + j] + bias_b[cb + j];
    }

    const int colg = colBase + tx * 4;
    const int gr = rowBase + ty * 4;
    #pragma unroll
    for (int i = 0; i < 4; ++i) {
        int g = gr + i;
        if (g < N_NODES) {
            float4 o;
            o.x = acc[i][0] + badd[0];
            o.y = acc[i][1] + badd[1];
            o.z = acc[i][2] + badd[2];
            o.w = acc[i][3] + badd[3];
            *(float4*)(O + (size_t)g * C + colg) = o;
        }
    }
}

// -------------------------------------------- layer-1 gather + lin + relu ---
// h1[n,f] = relu(dis[n] * sum_e w[e]*xw1[src[e],f] + lin1[n,f])  (in place)
__global__ __launch_bounds__(128) void k_gather1(
    const int* __restrict__ rowptr, const int2* __restrict__ edge,
    const float* __restrict__ dis,
    const float* __restrict__ xw1, float* __restrict__ lin1_h1) {
    const int n = blockIdx.x;
    const int f = threadIdx.x;
    const int start = rowptr[n], end = rowptr[n + 1];
    float acc = 0.f;
    int e = start;
    for (; e + 4 <= end; e += 4) {
        int2 e0 = edge[e], e1 = edge[e + 1], e2 = edge[e + 2], e3 = edge[e + 3];
        float v0 = xw1[(size_t)e0.x * 128 + f];
        float v1 = xw1[(size_t)e1.x * 128 + f];
        float v2 = xw1[(size_t)e2.x * 128 + f];
        float v3 = xw1[(size_t)e3.x * 128 + f];
        acc += __int_as_float(e0.y) * v0 + __int_as_float(e1.y) * v1
             + __int_as_float(e2.y) * v2 + __int_as_float(e3.y) * v3;
    }
    for (; e < end; ++e) {
        int2 ed = edge[e];
        acc += __int_as_float(ed.y) * xw1[(size_t)ed.x * 128 + f];
    }
    size_t o = (size_t)n * 128 + f;
    lin1_h1[o] = fmaxf(dis[n] * acc + lin1_h1[o], 0.f);
}

// ------------------------------- layer-2 gather + lin + pool-by-group add ---
__global__ __launch_bounds__(128) void k_gather2(
    const int* __restrict__ rowptr, const int2* __restrict__ edge,
    const float* __restrict__ dis,
    const float* __restrict__ hw2, const float* __restrict__ lin2,
    const int* __restrict__ group, float* __restrict__ pooled) {
    const int n = blockIdx.x * 2 + (threadIdx.x >> 6);
    const int f = threadIdx.x & 63;
    if (n >= N_NODES) return;
    const int start = rowptr[n], end = rowptr[n + 1];
    float acc = 0.f;
    int e = start;
    for (; e + 4 <= end; e += 4) {
        int2 e0 = edge[e], e1 = edge[e + 1], e2 = edge[e + 2], e3 = edge[e + 3];
        float v0 = hw2[(size_t)e0.x * 64 + f];
        float v1 = hw2[(size_t)e1.x * 64 + f];
        float v2 = hw2[(size_t)e2.x * 64 + f];
        float v3 = hw2[(size_t)e3.x * 64 + f];
        acc += __int_as_float(e0.y) * v0 + __int_as_float(e1.y) * v1
             + __int_as_float(e2.y) * v2 + __int_as_float(e3.y) * v3;
    }
    for (; e < end; ++e) {
        int2 ed = edge[e];
        acc += __int_as_float(ed.y) * hw2[(size_t)ed.x * 64 + f];
    }
    float h2 = dis[n] * acc + lin2[(size_t)n * 64 + f];
    atomicAdd(&pooled[(size_t)group[n] * 64 + f], h2);
}

// ----------------------------------------------------- head: relu @ Wh + bh -
__global__ __launch_bounds__(64) void k_head(
    const float* __restrict__ pooled, const float* __restrict__ Wh,
    const float* __restrict__ bh, float* __restrict__ out)
{
    int g = blockIdx.x;
    int f = threadIdx.x;
    float v = fmaxf(pooled[g * 64 + f], 0.f) * Wh[f];
    #pragma unroll
    for (int off = 32; off > 0; off >>= 1) v += __shfl_down(v, off);
    if (f == 0) out[g] = v + bh[0];
}

// ---------------------------------------------------------------------------
extern "C" void kernel_launch(void* const* d_in, const int* in_sizes, int n_in,
                              void* d_out, int out_size, void* d_ws, size_t ws_size,
                              hipStream_t stream) {
    const float* x  = (const float*)d_in[0];
    const int*   ei = (const int*)d_in[1];
    const int*  grp = (const int*)d_in[2];
    const float* W1 = (const float*)d_in[3];
    const float* b1 = (const float*)d_in[4];
    const float* L1 = (const float*)d_in[5];
    const float* c1 = (const float*)d_in[6];
    const float* W2 = (const float*)d_in[7];
    const float* b2 = (const float*)d_in[8];
    const float* L2 = (const float*)d_in[9];
    const float* c2 = (const float*)d_in[10];
    const float* Wh = (const float*)d_in[11];
    const float* bh = (const float*)d_in[12];
    float* out = (float*)d_out;

    const int* row  = ei;             // edge_index[0] = source
    const int* colp = ei + N_EDGES;   // edge_index[1] = target

    // ws layout (16B-aligned slabs)
    char* p = (char*)d_ws;
    float* dis    = (float*)p;             p += 50048 * 4;
    int*   ideg   = (int*)p;               p += 50048 * 4;
    int*   rowptr = (int*)p;               p += 50064 * 4;
    int*   cursor = (int*)p;               p += 50048 * 4;
    int*   bsum   = (int*)p;               p += 64 * 4;
    int*   boff   = (int*)p;               p += 64 * 4;
    int2*  edge   = (int2*)p;              p += (size_t)800000 * 8;
    float* xw1    = (float*)p;             p += (size_t)N_NODES * 128 * 4;
    float* lin1   = (float*)p;             p += (size_t)N_NODES * 128 * 4;
    float* pooled = (float*)p;             p += N_GROUPS * 64 * 4;
    float* hw2  = xw1;
    float* lin2 = xw1 + (size_t)N_NODES * 64;

    hipMemsetAsync(ideg, 0, N_NODES * sizeof(int), stream);
    hipMemsetAsync(pooled, 0, (size_t)N_GROUPS * 64 * sizeof(float), stream);

    // CSR build
    k_deg<<<(N_EDGES + 255) / 256, 256, 0, stream>>>(colp, ideg);
    k_scanA<<<SCAN_BLK, 256, 0, stream>>>(ideg, bsum);
    k_scanB<<<1, 64, 0, stream>>>(bsum, boff, rowptr);
    k_scanC<<<SCAN_BLK, 256, 0, stream>>>(ideg, boff, rowptr, cursor, dis);
    k_fill<<<(N_EDGES + 255) / 256, 256, 0, stream>>>(row, colp, dis, cursor, edge);

    dim3 blk(16, 16);
    // layer 1: xw1 = x@W1 ; lin1 = x@L1 + c1 + b1
    k_gemm_dual<<<dim3(782, 4), blk, 0, stream>>>(x, W1, L1, c1, b1, xw1, lin1, 128, 2);
    k_gather1<<<N_NODES, 128, 0, stream>>>(rowptr, edge, dis, xw1, lin1); // h1 in lin1

    // layer 2: hw2 = h1@W2 ; lin2 = h1@L2 + c2 + b2
    k_gemm_dual<<<dim3(782, 2), blk, 0, stream>>>(lin1, W2, L2, c2, b2, hw2, lin2, 64, 1);
    k_gather2<<<(N_NODES + 1) / 2, 128, 0, stream>>>(rowptr, edge, dis, hw2, lin2, grp, pooled);

    k_head<<<N_GROUPS, 64, 0, stream>>>(pooled, Wh, bh, out);
}